// Round 17
// baseline (499.309 us; speedup 1.0000x reference)
//
#include <hip/hip_runtime.h>
#include <hip/hip_bf16.h>
#include <math.h>

// Problem constants
#define SEQ 4096
#define LL  4097           // sequence + CLS
#define HDIM 32
#define NHEAD 8
#define HD 4
#define FFD 2048
#define NLAYER 6
#define EPSLN 1e-5f
#define NCHUNK 8           // split-K chunks over keys (512 keys each, last 544)
#define KPAD 4128          // keys 0..4096 padded to 129*32
#define QROWS 4224         // 33 blocks * 128 queries
#define XROWS 4160         // LL rounded up for direct bf16 A-fragment reads
#define RT 64              // FFN row tile
#define FS 128             // FFN f-segment width
#define NFS 16             // FFD / FS

#if __has_builtin(__builtin_amdgcn_exp2f)
#define EXP2 __builtin_amdgcn_exp2f
#else
#define EXP2 exp2f
#endif

#define QSCALE 0.7213475204444817f   // 0.5 * log2(e)

typedef short bf16x8 __attribute__((ext_vector_type(8)));
typedef float f32x4 __attribute__((ext_vector_type(4)));

__device__ __forceinline__ unsigned short f2b(float f) {   // fp32 -> bf16 RNE
  unsigned int b = __float_as_uint(f);
  b += 0x7FFFu + ((b >> 16) & 1u);
  return (unsigned short)(b >> 16);
}

__device__ __forceinline__ unsigned int pk_bf16(float a, float b) {
  __hip_bfloat162 h = __float22bfloat162_rn(make_float2(a, b));
  return *(unsigned int*)&h;
}

// Buffers:
//  Qb  [QROWS][32]  bf16, pre-scaled by QSCALE (pad rows zero)
//  KB  [8][KPAD][32] bf16, per-head zero-masked K (only dims h*4..h*4+3 set)
//  VBt [8][16][KPAD] bf16, rows 0..3 = V dims (permuted key order), row 4 =
//      validity ones, rows 5..15 = 0. Key permutation within 32-blocks:
//      pos = ((w&15)<<1) | (w>>4).
//  LP[(c*8+h)*LL+q] float, AP[(c*8+h)*LL+q] float4 — split-K partials.
//  Xb  [XROWS][32] bf16 — post-LN1 X, ffnA's GEMM1 A operand (direct global).

// ------ one-off setup: zero/init masked buffers + convert FFN weights -------
__global__ __launch_bounds__(256) void k_setup(const float* __restrict__ w1,
    const float* __restrict__ w2, unsigned short* __restrict__ w1b,
    unsigned short* __restrict__ w2b, unsigned short* __restrict__ Qb,
    unsigned short* __restrict__ KB, unsigned short* __restrict__ VBt) {
  const int NW = NLAYER * FFD * 32;
  const int NQ = QROWS * 32;
  const int NK = 8 * KPAD * 32;
  const int NV = 8 * 16 * KPAD;
  int idx = blockIdx.x * 256 + threadIdx.x;
  if (idx < NW) {
    w1b[idx] = f2b(w1[idx]);
    w2b[idx] = f2b(w2[idx]);
  }
  if (idx < NQ) Qb[idx] = 0;
  if (idx < NK) KB[idx] = 0;
  if (idx < NV) {
    int i = idx % KPAD;
    int d = (idx / KPAD) & 15;
    unsigned short v = 0;
    if (d == 4) {
      int key = (i & ~31) + ((i & 1) << 4) + ((i & 31) >> 1);
      if (key <= 4096) v = 0x3F80;   // bf16 1.0
    }
    VBt[idx] = v;
  }
}

__device__ __forceinline__ void store_qkv_bf16(int row, int ch, int t3,
    float acc, unsigned short* __restrict__ Qb, unsigned short* __restrict__ KB,
    unsigned short* __restrict__ VBt) {
  int h = ch >> 2, d = ch & 3;
  if (t3 == 0) {
    Qb[(size_t)row * 32 + ch] = f2b(QSCALE * acc);
  } else if (t3 == 1) {
    KB[((size_t)h * KPAD + row) * 32 + ch] = f2b(acc);
  } else {
    int w = row & 31;
    int pos = ((w & 15) << 1) | (w >> 4);
    VBt[((size_t)h * 16 + d) * KPAD + (row & ~31) + pos] = f2b(acc);
  }
}

// -------- embed (relu(lin)+PE, CLS=-1) fused with layer-0 qkv ---------------
__global__ __launch_bounds__(256) void k_embed_qkv(const float* __restrict__ data,
    const float* __restrict__ lin_w, const float* __restrict__ lin_b,
    float* __restrict__ x, const float* __restrict__ qw,
    const float* __restrict__ qb, unsigned short* __restrict__ Qb,
    unsigned short* __restrict__ KB, unsigned short* __restrict__ VBt) {
  __shared__ float xs[8][33];
  int tid = threadIdx.x;
  int r = tid >> 5, ch = tid & 31;
  int row = blockIdx.x * 8 + r;
  bool ok = row < LL;
  float val = 0.f;
  if (ok) {
    if (row == 0) {
      val = -1.0f;
    } else {
      int s = row - 1;
      float ts = data[s * 3 + 0];
      float f0 = data[s * 3 + 1];
      float f1 = data[s * 3 + 2];
      float lin = f0 * lin_w[ch * 2 + 0] + f1 * lin_w[ch * 2 + 1] + lin_b[ch];
      lin = fmaxf(lin, 0.0f);
      int tsi = (int)(ts / 100.0f);
      int j = ch >> 1;
      float aj = (float)(2 * j) * (float)(-0.28782313662425575);
      float divj = (float)exp((double)aj);
      float ang = (float)tsi * divj;
      float pe = (ch & 1) ? cosf(ang) : sinf(ang);
      val = lin + pe;
    }
    x[(size_t)row * HDIM + ch] = val;
  }
  xs[r][ch] = val;
  __syncthreads();
  if (!ok) return;
#pragma unroll
  for (int t3 = 0; t3 < 3; ++t3) {
    int cc = t3 * 32 + ch;
    const float4* wr = (const float4*)(qw + (size_t)cc * HDIM);
    float acc = qb[cc];
#pragma unroll
    for (int k = 0; k < 8; ++k) {
      float4 wv = wr[k];
      acc = fmaf(xs[r][4 * k + 0], wv.x, acc);
      acc = fmaf(xs[r][4 * k + 1], wv.y, acc);
      acc = fmaf(xs[r][4 * k + 2], wv.z, acc);
      acc = fmaf(xs[r][4 * k + 3], wv.w, acc);
    }
    store_qkv_bf16(row, ch, t3, acc, Qb, KB, VBt);
  }
}

// ---- attention via MFMA, 3-stage software pipeline -------------------------
// grid (33, NHEAD, NCHUNK). Block = 4 waves; wave owns 2 q-tiles (32 queries).
// chunk c: keys c*512 .. +511 (c==7: +543, includes key 4096 + zero pads).
// Three kb-iterations in flight with disjoint Pt buffers and disjoint
// accumulators -> 3 independent mfma->exp2->LDS->mfma chains per wave.
__global__ __launch_bounds__(256, 6) void k_attn(
    const unsigned short* __restrict__ Qb, const unsigned short* __restrict__ KB,
    const unsigned short* __restrict__ VBt, float* __restrict__ LP,
    float* __restrict__ APf) {
  __shared__ unsigned short Pt[4][6][16 * 40];
  int tid = threadIdx.x;
  int wave = tid >> 6, lane = tid & 63;
  int l16 = lane & 15, quad = lane >> 4;
  int h = blockIdx.y, c = blockIdx.z;
  int q0 = (blockIdx.x * 4 + wave) * 32;
  int kb0 = c * 512;
  int nkb = (c == NCHUNK - 1) ? 17 : 16;

  const unsigned short* KBh = KB + (size_t)h * KPAD * 32;
  const unsigned short* VBh = VBt + (size_t)h * 16 * KPAD;

  bf16x8 aq0 = *(const bf16x8*)&Qb[(size_t)(q0 + l16) * 32 + quad * 8];
  bf16x8 aq1 = *(const bf16x8*)&Qb[(size_t)(q0 + 16 + l16) * 32 + quad * 8];

  f32x4 accA0 = {0.f, 0.f, 0.f, 0.f}, accB0 = {0.f, 0.f, 0.f, 0.f};
  f32x4 accA1 = {0.f, 0.f, 0.f, 0.f}, accB1 = {0.f, 0.f, 0.f, 0.f};
  f32x4 accA2 = {0.f, 0.f, 0.f, 0.f}, accB2 = {0.f, 0.f, 0.f, 0.f};

  auto step = [&](int k0, unsigned short* P0, unsigned short* P1,
                  f32x4& cA, f32x4& cB) {
    bf16x8 bk0 = *(const bf16x8*)&KBh[(size_t)(k0 + l16) * 32 + quad * 8];
    bf16x8 bk1 = *(const bf16x8*)&KBh[(size_t)(k0 + 16 + l16) * 32 + quad * 8];
    f32x4 z = {0.f, 0.f, 0.f, 0.f};
    f32x4 s00 = __builtin_amdgcn_mfma_f32_16x16x32_bf16(aq0, bk0, z, 0, 0, 0);
    f32x4 s01 = __builtin_amdgcn_mfma_f32_16x16x32_bf16(aq0, bk1, z, 0, 0, 0);
    f32x4 s10 = __builtin_amdgcn_mfma_f32_16x16x32_bf16(aq1, bk0, z, 0, 0, 0);
    f32x4 s11 = __builtin_amdgcn_mfma_f32_16x16x32_bf16(aq1, bk1, z, 0, 0, 0);
#pragma unroll
    for (int reg = 0; reg < 4; ++reg) {
      int row = quad * 4 + reg;
      *(unsigned int*)&P0[row * 40 + l16 * 2] =
          pk_bf16(EXP2(s00[reg]), EXP2(s01[reg]));
      *(unsigned int*)&P1[row * 40 + l16 * 2] =
          pk_bf16(EXP2(s10[reg]), EXP2(s11[reg]));
    }
    // wave-private LDS transpose (lockstep wave: no barrier needed)
    bf16x8 a2q0 = *(const bf16x8*)&P0[l16 * 40 + quad * 8];
    bf16x8 a2q1 = *(const bf16x8*)&P1[l16 * 40 + quad * 8];
    bf16x8 bv = *(const bf16x8*)&VBh[(size_t)l16 * KPAD + k0 + quad * 8];
    cA = __builtin_amdgcn_mfma_f32_16x16x32_bf16(a2q0, bv, cA, 0, 0, 0);
    cB = __builtin_amdgcn_mfma_f32_16x16x32_bf16(a2q1, bv, cB, 0, 0, 0);
  };

  int kb = 0;
  for (; kb + 3 <= nkb; kb += 3) {
    step(kb0 + kb * 32, &Pt[wave][0][0], &Pt[wave][1][0], accA0, accB0);
    step(kb0 + (kb + 1) * 32, &Pt[wave][2][0], &Pt[wave][3][0], accA1, accB1);
    step(kb0 + (kb + 2) * 32, &Pt[wave][4][0], &Pt[wave][5][0], accA2, accB2);
  }
  if (kb < nkb) {
    step(kb0 + kb * 32, &Pt[wave][0][0], &Pt[wave][1][0], accA0, accB0);
    ++kb;
  }
  if (kb < nkb)
    step(kb0 + kb * 32, &Pt[wave][2][0], &Pt[wave][3][0], accA1, accB1);

  f32x4 accA = (accA0 + accA1) + accA2;
  f32x4 accB = (accB0 + accB1) + accB2;

  size_t base = ((size_t)c * NHEAD + h) * LL;
#pragma unroll
  for (int reg = 0; reg < 4; ++reg) {
    int q = q0 + quad * 4 + reg;
    int q2 = q + 16;
    if (l16 < 4) {
      if (q < LL) APf[(base + q) * 4 + l16] = accA[reg];
      if (q2 < LL) APf[(base + q2) * 4 + l16] = accB[reg];
    } else if (l16 == 4) {
      if (q < LL) LP[base + q] = accA[reg];
      if (q2 < LL) LP[base + q2] = accB[reg];
    }
  }
}

// ------- fused: sum split-K partials + o-proj + residual + LN1 --------------
// Writes X (fp32, ffnB residual) AND Xb (bf16, ffnA's A operand).
__global__ __launch_bounds__(256) void k_oproj(const float* __restrict__ LP,
    const float4* __restrict__ AP, float* __restrict__ x,
    unsigned short* __restrict__ Xb,
    const float* __restrict__ ow, const float* __restrict__ ob,
    const float* __restrict__ g, const float* __restrict__ bln) {
  int tid = threadIdx.x;
  int r = tid >> 5, ch = tid & 31;
  int row = blockIdx.x * 8 + r;
  __shared__ float os[8][32];
  bool ok = row < LL;
  if (ok) {
    int h = ch >> 2, d = ch & 3;
    float L = 0.f, A = 0.f;
#pragma unroll
    for (int c = 0; c < NCHUNK; ++c) {
      size_t idx = ((size_t)c * NHEAD + h) * LL + row;
      L += LP[idx];
      A += ((const float*)&AP[idx])[d];
    }
    os[r][ch] = A / L;
  } else {
    os[r][ch] = 0.f;
  }
  __syncthreads();
  float acc = 0.f;
#pragma unroll
  for (int k = 0; k < 32; ++k) acc = fmaf(os[r][k], ow[ch * 32 + k], acc);
  float val = ok ? (x[(size_t)row * HDIM + ch] + acc + ob[ch]) : 0.f;
  float mean = val;
#pragma unroll
  for (int off = 16; off > 0; off >>= 1) mean += __shfl_xor(mean, off, 32);
  mean *= (1.f / 32.f);
  float d2 = val - mean;
  float var = d2 * d2;
#pragma unroll
  for (int off = 16; off > 0; off >>= 1) var += __shfl_xor(var, off, 32);
  var *= (1.f / 32.f);
  float y = d2 / sqrtf(var + EPSLN) * g[ch] + bln[ch];
  if (ok) {
    x[(size_t)row * HDIM + ch] = y;
    Xb[(size_t)row * HDIM + ch] = f2b(y);
  }
}

// ---------------- FFN part A via MFMA bf16 ----------------------------------
// GEMM1 A-fragments read directly from global Xb (no LDS staging / no f2b).
__global__ __launch_bounds__(256) void k_ffnA(
    const unsigned short* __restrict__ Xb,
    const unsigned short* __restrict__ w1b, const float* __restrict__ b1,
    const unsigned short* __restrict__ w2b, float* __restrict__ part2) {
  __shared__ unsigned short Fsb[RT * 136];
  int tid = threadIdx.x;
  int r0 = blockIdx.x * RT;
  int f0 = blockIdx.y * FS;
  int wave = tid >> 6, lane = tid & 63;
  int l16 = lane & 15, quad = lane >> 4;
  int m0 = wave * 16;

  bf16x8 a1 = *(const bf16x8*)&Xb[(size_t)(r0 + m0 + l16) * 32 + quad * 8];
  f32x4 c1[8];
#pragma unroll
  for (int t = 0; t < 8; ++t) {
    bf16x8 b =
        *(const bf16x8*)&w1b[(size_t)(f0 + t * 16 + l16) * 32 + quad * 8];
    f32x4 z = {0.f, 0.f, 0.f, 0.f};
    c1[t] = __builtin_amdgcn_mfma_f32_16x16x32_bf16(a1, b, z, 0, 0, 0);
  }
#pragma unroll
  for (int t = 0; t < 8; ++t) {
    float bb = b1[f0 + t * 16 + l16];
#pragma unroll
    for (int reg = 0; reg < 4; ++reg) {
      float v = fmaxf(c1[t][reg] + bb, 0.f);
      int rrow = m0 + quad * 4 + reg;
      Fsb[rrow * 136 + t * 16 + l16] = f2b(v);
    }
  }
  __syncthreads();

  f32x4 acc[2] = {{0.f, 0.f, 0.f, 0.f}, {0.f, 0.f, 0.f, 0.f}};
#pragma unroll
  for (int kt = 0; kt < 4; ++kt) {
    bf16x8 a2 = *(const bf16x8*)&Fsb[(m0 + l16) * 136 + kt * 32 + quad * 8];
#pragma unroll
    for (int u = 0; u < 2; ++u) {
      bf16x8 b =
          *(const bf16x8*)&w2b[(size_t)(u * 16 + l16) * FFD + f0 + kt * 32 + quad * 8];
      acc[u] = __builtin_amdgcn_mfma_f32_16x16x32_bf16(a2, b, acc[u], 0, 0, 0);
    }
  }
#pragma unroll
  for (int u = 0; u < 2; ++u) {
#pragma unroll
    for (int reg = 0; reg < 4; ++reg) {
      int rrow = r0 + m0 + quad * 4 + reg;
      if (rrow < LL)
        part2[((size_t)blockIdx.y * LL + rrow) * HDIM + u * 16 + l16] =
            acc[u][reg];
    }
  }
}

// ------ FFN part B: combine + residual + LN2 + next qkv (bf16) + final ------
__global__ __launch_bounds__(256) void k_ffnB_qkv(float* __restrict__ x,
    const float* __restrict__ part2, const float* __restrict__ b2,
    const float* __restrict__ g, const float* __restrict__ bln,
    const float* __restrict__ qw, const float* __restrict__ qb,
    unsigned short* __restrict__ Qb, unsigned short* __restrict__ KB,
    unsigned short* __restrict__ VBt, int do_qkv,
    const float* __restrict__ cw, const float* __restrict__ cb,
    float* __restrict__ out) {
  __shared__ float xs[8][33];
  int tid = threadIdx.x;
  int r = tid >> 5, ch = tid & 31;
  int row = blockIdx.x * 8 + r;
  bool ok = row < LL;
  float s = 0.f;
  if (ok) {
#pragma unroll
    for (int q = 0; q < NFS; ++q)
      s += part2[((size_t)q * LL + row) * HDIM + ch];
  }
  float val = ok ? (x[(size_t)row * HDIM + ch] + s + b2[ch]) : 0.f;
  float mean = val;
#pragma unroll
  for (int off = 16; off > 0; off >>= 1) mean += __shfl_xor(mean, off, 32);
  mean *= (1.f / 32.f);
  float d = val - mean;
  float var = d * d;
#pragma unroll
  for (int off = 16; off > 0; off >>= 1) var += __shfl_xor(var, off, 32);
  var *= (1.f / 32.f);
  float y = d / sqrtf(var + EPSLN) * g[ch] + bln[ch];
  if (ok) x[(size_t)row * HDIM + ch] = y;
  xs[r][ch] = ok ? y : 0.f;
  __syncthreads();
  if (!do_qkv) {
    if (blockIdx.x == 0 && r == 0) {
      float t = y * cw[ch];
#pragma unroll
      for (int off = 16; off > 0; off >>= 1) t += __shfl_xor(t, off, 32);
      if (ch == 0) {
        float z = t + cb[0];
        out[0] = 1.f / (1.f + expf(-z));
      }
    }
    return;
  }
  if (!ok) return;
#pragma unroll
  for (int t3 = 0; t3 < 3; ++t3) {
    int cc = t3 * 32 + ch;
    const float4* wr = (const float4*)(qw + (size_t)cc * HDIM);
    float acc = qb[cc];
#pragma unroll
    for (int k = 0; k < 8; ++k) {
      float4 wv = wr[k];
      acc = fmaf(xs[r][4 * k + 0], wv.x, acc);
      acc = fmaf(xs[r][4 * k + 1], wv.y, acc);
      acc = fmaf(xs[r][4 * k + 2], wv.z, acc);
      acc = fmaf(xs[r][4 * k + 3], wv.w, acc);
    }
    store_qkv_bf16(row, ch, t3, acc, Qb, KB, VBt);
  }
}

extern "C" void kernel_launch(void* const* d_in, const int* in_sizes, int n_in,
                              void* d_out, int out_size, void* d_ws, size_t ws_size,
                              hipStream_t stream) {
  const float* data  = (const float*)d_in[0];
  const float* lin_w = (const float*)d_in[1];
  const float* lin_b = (const float*)d_in[2];
  const float* qkv_w = (const float*)d_in[3];
  const float* qkv_b = (const float*)d_in[4];
  const float* out_w = (const float*)d_in[5];
  const float* out_b = (const float*)d_in[6];
  const float* ln1_g = (const float*)d_in[7];
  const float* ln1_b = (const float*)d_in[8];
  const float* ff1_w = (const float*)d_in[9];
  const float* ff1_b = (const float*)d_in[10];
  const float* ff2_w = (const float*)d_in[11];
  const float* ff2_b = (const float*)d_in[12];
  const float* ln2_g = (const float*)d_in[13];
  const float* ln2_b = (const float*)d_in[14];
  const float* cls_w = (const float*)d_in[15];
  const float* cls_b = (const float*)d_in[16];

  float* ws = (float*)d_ws;
  float* X = ws;                                       // LL*32 fp32
  unsigned short* Xb  = (unsigned short*)(X + (size_t)LL * 32);  // XROWS*32
  unsigned short* Qb  = Xb + (size_t)XROWS * 32;
  unsigned short* KB  = Qb + (size_t)QROWS * 32;       // 8*KPAD*32
  unsigned short* VBt = KB + (size_t)8 * KPAD * 32;    // 8*16*KPAD
  unsigned short* W1B = VBt + (size_t)8 * 16 * KPAD;   // NL*FFD*32
  unsigned short* W2B = W1B + (size_t)NLAYER * FFD * 32;
  float4* AP = (float4*)(((size_t)(W2B + (size_t)NLAYER * FFD * 32) + 15) &
                         ~(size_t)15);                 // NCHUNK*NHEAD*LL float4
  float* LP = (float*)(AP + (size_t)NCHUNK * NHEAD * LL);
  float* PART2 = (float*)AP;   // aliased; extends past LP into free ws space

  const int NROWB = (LL + 7) / 8;                      // 513
  const int NSETUP = 8 * KPAD * 32;                    // largest setup region

  k_setup<<<(NSETUP + 255) / 256, 256, 0, stream>>>(ff1_w, ff2_w, W1B, W2B,
                                                    Qb, KB, VBt);
  k_embed_qkv<<<NROWB, 256, 0, stream>>>(data, lin_w, lin_b, X,
                                         qkv_w, qkv_b, Qb, KB, VBt);
  for (int l = 0; l < NLAYER; ++l) {
    k_attn<<<dim3(33, NHEAD, NCHUNK), 256, 0, stream>>>(Qb, KB, VBt, LP,
                                                        (float*)AP);
    k_oproj<<<NROWB, 256, 0, stream>>>(
        LP, AP, X, Xb, out_w + (size_t)l * 32 * 32, out_b + (size_t)l * 32,
        ln1_g + (size_t)l * 32, ln1_b + (size_t)l * 32);
    k_ffnA<<<dim3((LL + RT - 1) / RT, NFS), 256, 0, stream>>>(
        Xb, W1B + (size_t)l * FFD * 32, ff1_b + (size_t)l * FFD,
        W2B + (size_t)l * FFD * 32, PART2);
    int nl = l + 1;
    int do_qkv = (nl < NLAYER) ? 1 : 0;
    const float* qw = qkv_w + (size_t)(do_qkv ? nl : 0) * 96 * 32;
    const float* qb = qkv_b + (size_t)(do_qkv ? nl : 0) * 96;
    k_ffnB_qkv<<<NROWB, 256, 0, stream>>>(
        X, PART2, ff2_b + (size_t)l * 32,
        ln2_g + (size_t)l * 32, ln2_b + (size_t)l * 32,
        qw, qb, Qb, KB, VBt, do_qkv, cls_w, cls_b, (float*)d_out);
  }
}

// Round 18
// 487.317 us; speedup vs baseline: 1.0246x; 1.0246x over previous
//
#include <hip/hip_runtime.h>
#include <hip/hip_bf16.h>
#include <math.h>

// Problem constants
#define SEQ 4096
#define LL  4097           // sequence + CLS
#define HDIM 32
#define NHEAD 8
#define HD 4
#define FFD 2048
#define NLAYER 6
#define EPSLN 1e-5f
#define NCHUNK 16          // split-K chunks over keys (256 keys each, last 288)
#define KPAD 4128          // keys 0..4096 padded to 129*32
#define QROWS 4224         // 33 blocks * 128 queries
#define XROWS 4160         // LL rounded up for direct bf16 A-fragment reads
#define RT 64              // FFN row tile
#define FS 128             // FFN f-segment width
#define NSEG 8             // part2 segments (2 f-segments fused per block)

#if __has_builtin(__builtin_amdgcn_exp2f)
#define EXP2 __builtin_amdgcn_exp2f
#else
#define EXP2 exp2f
#endif

#define QSCALE 0.7213475204444817f   // 0.5 * log2(e)

typedef short bf16x8 __attribute__((ext_vector_type(8)));
typedef float f32x4 __attribute__((ext_vector_type(4)));

__device__ __forceinline__ unsigned short f2b(float f) {   // fp32 -> bf16 RNE
  unsigned int b = __float_as_uint(f);
  b += 0x7FFFu + ((b >> 16) & 1u);
  return (unsigned short)(b >> 16);
}

__device__ __forceinline__ unsigned int pk_bf16(float a, float b) {
  __hip_bfloat162 h = __float22bfloat162_rn(make_float2(a, b));
  return *(unsigned int*)&h;
}

// Buffers:
//  Qb  [QROWS][32]  bf16, pre-scaled by QSCALE (pad rows zero)
//  KB  [8][KPAD][32] bf16, per-head zero-masked K (only dims h*4..h*4+3 set)
//  VBt [8][16][KPAD] bf16, rows 0..3 = V dims (permuted key order), row 4 =
//      validity ones, rows 5..15 = 0. Key permutation within 32-blocks:
//      pos = ((w&15)<<1) | (w>>4).
//  LP[(c*8+h)*LL+q] float, AP[(c*8+h)*LL+q] float4 — split-K partials.
//  Xb  [XROWS][32] bf16 — post-LN1 X, ffnA's GEMM1 A operand (direct global).

// ------ one-off setup: zero/init masked buffers + convert FFN weights -------
__global__ __launch_bounds__(256) void k_setup(const float* __restrict__ w1,
    const float* __restrict__ w2, unsigned short* __restrict__ w1b,
    unsigned short* __restrict__ w2b, unsigned short* __restrict__ Qb,
    unsigned short* __restrict__ KB, unsigned short* __restrict__ VBt) {
  const int NW = NLAYER * FFD * 32;
  const int NQ = QROWS * 32;
  const int NK = 8 * KPAD * 32;
  const int NV = 8 * 16 * KPAD;
  int idx = blockIdx.x * 256 + threadIdx.x;
  if (idx < NW) {
    w1b[idx] = f2b(w1[idx]);
    w2b[idx] = f2b(w2[idx]);
  }
  if (idx < NQ) Qb[idx] = 0;
  if (idx < NK) KB[idx] = 0;
  if (idx < NV) {
    int i = idx % KPAD;
    int d = (idx / KPAD) & 15;
    unsigned short v = 0;
    if (d == 4) {
      int key = (i & ~31) + ((i & 1) << 4) + ((i & 31) >> 1);
      if (key <= 4096) v = 0x3F80;   // bf16 1.0
    }
    VBt[idx] = v;
  }
}

__device__ __forceinline__ void store_qkv_bf16(int row, int ch, int t3,
    float acc, unsigned short* __restrict__ Qb, unsigned short* __restrict__ KB,
    unsigned short* __restrict__ VBt) {
  int h = ch >> 2, d = ch & 3;
  if (t3 == 0) {
    Qb[(size_t)row * 32 + ch] = f2b(QSCALE * acc);
  } else if (t3 == 1) {
    KB[((size_t)h * KPAD + row) * 32 + ch] = f2b(acc);
  } else {
    int w = row & 31;
    int pos = ((w & 15) << 1) | (w >> 4);
    VBt[((size_t)h * 16 + d) * KPAD + (row & ~31) + pos] = f2b(acc);
  }
}

// -------- embed (relu(lin)+PE, CLS=-1) fused with layer-0 qkv ---------------
__global__ __launch_bounds__(256) void k_embed_qkv(const float* __restrict__ data,
    const float* __restrict__ lin_w, const float* __restrict__ lin_b,
    float* __restrict__ x, const float* __restrict__ qw,
    const float* __restrict__ qb, unsigned short* __restrict__ Qb,
    unsigned short* __restrict__ KB, unsigned short* __restrict__ VBt) {
  __shared__ float xs[8][33];
  int tid = threadIdx.x;
  int r = tid >> 5, ch = tid & 31;
  int row = blockIdx.x * 8 + r;
  bool ok = row < LL;
  float val = 0.f;
  if (ok) {
    if (row == 0) {
      val = -1.0f;
    } else {
      int s = row - 1;
      float ts = data[s * 3 + 0];
      float f0 = data[s * 3 + 1];
      float f1 = data[s * 3 + 2];
      float lin = f0 * lin_w[ch * 2 + 0] + f1 * lin_w[ch * 2 + 1] + lin_b[ch];
      lin = fmaxf(lin, 0.0f);
      int tsi = (int)(ts / 100.0f);
      int j = ch >> 1;
      float aj = (float)(2 * j) * (float)(-0.28782313662425575);
      float divj = (float)exp((double)aj);
      float ang = (float)tsi * divj;
      float pe = (ch & 1) ? cosf(ang) : sinf(ang);
      val = lin + pe;
    }
    x[(size_t)row * HDIM + ch] = val;
  }
  xs[r][ch] = val;
  __syncthreads();
  if (!ok) return;
#pragma unroll
  for (int t3 = 0; t3 < 3; ++t3) {
    int cc = t3 * 32 + ch;
    const float4* wr = (const float4*)(qw + (size_t)cc * HDIM);
    float acc = qb[cc];
#pragma unroll
    for (int k = 0; k < 8; ++k) {
      float4 wv = wr[k];
      acc = fmaf(xs[r][4 * k + 0], wv.x, acc);
      acc = fmaf(xs[r][4 * k + 1], wv.y, acc);
      acc = fmaf(xs[r][4 * k + 2], wv.z, acc);
      acc = fmaf(xs[r][4 * k + 3], wv.w, acc);
    }
    store_qkv_bf16(row, ch, t3, acc, Qb, KB, VBt);
  }
}

// ---- attention via MFMA, 2-stage software pipeline (r15 config) ------------
// grid (33, NHEAD, NCHUNK). Block = 4 waves; wave owns 2 q-tiles (32 queries).
// chunk c: keys c*256 .. +255 (c==15: +287, includes key 4096 + zero pads).
__global__ __launch_bounds__(256, 6) void k_attn(
    const unsigned short* __restrict__ Qb, const unsigned short* __restrict__ KB,
    const unsigned short* __restrict__ VBt, float* __restrict__ LP,
    float* __restrict__ APf) {
  __shared__ unsigned short Pt[4][4][16 * 40];
  int tid = threadIdx.x;
  int wave = tid >> 6, lane = tid & 63;
  int l16 = lane & 15, quad = lane >> 4;
  int h = blockIdx.y, c = blockIdx.z;
  int q0 = (blockIdx.x * 4 + wave) * 32;
  int kb0 = c * 256;
  int nkb = (c == NCHUNK - 1) ? 9 : 8;

  const unsigned short* KBh = KB + (size_t)h * KPAD * 32;
  const unsigned short* VBh = VBt + (size_t)h * 16 * KPAD;

  bf16x8 aq0 = *(const bf16x8*)&Qb[(size_t)(q0 + l16) * 32 + quad * 8];
  bf16x8 aq1 = *(const bf16x8*)&Qb[(size_t)(q0 + 16 + l16) * 32 + quad * 8];

  f32x4 accA0 = {0.f, 0.f, 0.f, 0.f}, accB0 = {0.f, 0.f, 0.f, 0.f};
  f32x4 accA1 = {0.f, 0.f, 0.f, 0.f}, accB1 = {0.f, 0.f, 0.f, 0.f};

  auto step = [&](int k0, unsigned short* P0, unsigned short* P1,
                  f32x4& cA, f32x4& cB) {
    bf16x8 bk0 = *(const bf16x8*)&KBh[(size_t)(k0 + l16) * 32 + quad * 8];
    bf16x8 bk1 = *(const bf16x8*)&KBh[(size_t)(k0 + 16 + l16) * 32 + quad * 8];
    f32x4 z = {0.f, 0.f, 0.f, 0.f};
    f32x4 s00 = __builtin_amdgcn_mfma_f32_16x16x32_bf16(aq0, bk0, z, 0, 0, 0);
    f32x4 s01 = __builtin_amdgcn_mfma_f32_16x16x32_bf16(aq0, bk1, z, 0, 0, 0);
    f32x4 s10 = __builtin_amdgcn_mfma_f32_16x16x32_bf16(aq1, bk0, z, 0, 0, 0);
    f32x4 s11 = __builtin_amdgcn_mfma_f32_16x16x32_bf16(aq1, bk1, z, 0, 0, 0);
#pragma unroll
    for (int reg = 0; reg < 4; ++reg) {
      int row = quad * 4 + reg;
      *(unsigned int*)&P0[row * 40 + l16 * 2] =
          pk_bf16(EXP2(s00[reg]), EXP2(s01[reg]));
      *(unsigned int*)&P1[row * 40 + l16 * 2] =
          pk_bf16(EXP2(s10[reg]), EXP2(s11[reg]));
    }
    // wave-private LDS transpose (lockstep wave: no barrier needed)
    bf16x8 a2q0 = *(const bf16x8*)&P0[l16 * 40 + quad * 8];
    bf16x8 a2q1 = *(const bf16x8*)&P1[l16 * 40 + quad * 8];
    bf16x8 bv = *(const bf16x8*)&VBh[(size_t)l16 * KPAD + k0 + quad * 8];
    cA = __builtin_amdgcn_mfma_f32_16x16x32_bf16(a2q0, bv, cA, 0, 0, 0);
    cB = __builtin_amdgcn_mfma_f32_16x16x32_bf16(a2q1, bv, cB, 0, 0, 0);
  };

  int kb = 0;
  for (; kb + 2 <= nkb; kb += 2) {
    step(kb0 + kb * 32, &Pt[wave][0][0], &Pt[wave][1][0], accA0, accB0);
    step(kb0 + (kb + 1) * 32, &Pt[wave][2][0], &Pt[wave][3][0], accA1, accB1);
  }
  if (kb < nkb)
    step(kb0 + kb * 32, &Pt[wave][0][0], &Pt[wave][1][0], accA0, accB0);

  f32x4 accA = accA0 + accA1;
  f32x4 accB = accB0 + accB1;

  size_t base = ((size_t)c * NHEAD + h) * LL;
#pragma unroll
  for (int reg = 0; reg < 4; ++reg) {
    int q = q0 + quad * 4 + reg;
    int q2 = q + 16;
    if (l16 < 4) {
      if (q < LL) APf[(base + q) * 4 + l16] = accA[reg];
      if (q2 < LL) APf[(base + q2) * 4 + l16] = accB[reg];
    } else if (l16 == 4) {
      if (q < LL) LP[base + q] = accA[reg];
      if (q2 < LL) LP[base + q2] = accB[reg];
    }
  }
}

// ------- fused: sum split-K partials + o-proj + residual + LN1 --------------
// Writes X (fp32, ffnB residual) AND Xb (bf16, ffnA's A operand).
__global__ __launch_bounds__(256) void k_oproj(const float* __restrict__ LP,
    const float4* __restrict__ AP, float* __restrict__ x,
    unsigned short* __restrict__ Xb,
    const float* __restrict__ ow, const float* __restrict__ ob,
    const float* __restrict__ g, const float* __restrict__ bln) {
  int tid = threadIdx.x;
  int r = tid >> 5, ch = tid & 31;
  int row = blockIdx.x * 8 + r;
  __shared__ float os[8][32];
  bool ok = row < LL;
  if (ok) {
    int h = ch >> 2, d = ch & 3;
    float L = 0.f, A = 0.f;
#pragma unroll
    for (int c = 0; c < NCHUNK; ++c) {
      size_t idx = ((size_t)c * NHEAD + h) * LL + row;
      L += LP[idx];
      A += ((const float*)&AP[idx])[d];
    }
    os[r][ch] = A / L;
  } else {
    os[r][ch] = 0.f;
  }
  __syncthreads();
  float acc = 0.f;
#pragma unroll
  for (int k = 0; k < 32; ++k) acc = fmaf(os[r][k], ow[ch * 32 + k], acc);
  float val = ok ? (x[(size_t)row * HDIM + ch] + acc + ob[ch]) : 0.f;
  float mean = val;
#pragma unroll
  for (int off = 16; off > 0; off >>= 1) mean += __shfl_xor(mean, off, 32);
  mean *= (1.f / 32.f);
  float d2 = val - mean;
  float var = d2 * d2;
#pragma unroll
  for (int off = 16; off > 0; off >>= 1) var += __shfl_xor(var, off, 32);
  var *= (1.f / 32.f);
  float y = d2 / sqrtf(var + EPSLN) * g[ch] + bln[ch];
  if (ok) {
    x[(size_t)row * HDIM + ch] = y;
    Xb[(size_t)row * HDIM + ch] = f2b(y);
  }
}

// ---------------- FFN part A via MFMA bf16, 2 f-segments per block ----------
// grid (65, 8). A-fragments direct from global Xb. GEMM2 accumulates both
// segments in-register -> part2 has NSEG=8 partials.
__global__ __launch_bounds__(256) void k_ffnA(
    const unsigned short* __restrict__ Xb,
    const unsigned short* __restrict__ w1b, const float* __restrict__ b1,
    const unsigned short* __restrict__ w2b, float* __restrict__ part2) {
  __shared__ unsigned short Fsb[RT * 136];
  int tid = threadIdx.x;
  int r0 = blockIdx.x * RT;
  int wave = tid >> 6, lane = tid & 63;
  int l16 = lane & 15, quad = lane >> 4;
  int m0 = wave * 16;

  bf16x8 a1 = *(const bf16x8*)&Xb[(size_t)(r0 + m0 + l16) * 32 + quad * 8];
  f32x4 acc[2] = {{0.f, 0.f, 0.f, 0.f}, {0.f, 0.f, 0.f, 0.f}};

#pragma unroll
  for (int sg = 0; sg < 2; ++sg) {
    int f0 = (blockIdx.y * 2 + sg) * FS;
    f32x4 c1[8];
#pragma unroll
    for (int t = 0; t < 8; ++t) {
      bf16x8 b =
          *(const bf16x8*)&w1b[(size_t)(f0 + t * 16 + l16) * 32 + quad * 8];
      f32x4 z = {0.f, 0.f, 0.f, 0.f};
      c1[t] = __builtin_amdgcn_mfma_f32_16x16x32_bf16(a1, b, z, 0, 0, 0);
    }
    if (sg) __syncthreads();   // prev segment's Fsb reads complete
#pragma unroll
    for (int t = 0; t < 8; ++t) {
      float bb = b1[f0 + t * 16 + l16];
#pragma unroll
      for (int reg = 0; reg < 4; ++reg) {
        float v = fmaxf(c1[t][reg] + bb, 0.f);
        int rrow = m0 + quad * 4 + reg;
        Fsb[rrow * 136 + t * 16 + l16] = f2b(v);
      }
    }
    __syncthreads();
#pragma unroll
    for (int kt = 0; kt < 4; ++kt) {
      bf16x8 a2 = *(const bf16x8*)&Fsb[(m0 + l16) * 136 + kt * 32 + quad * 8];
#pragma unroll
      for (int u = 0; u < 2; ++u) {
        bf16x8 b = *(const bf16x8*)&w2b[(size_t)(u * 16 + l16) * FFD + f0 +
                                        kt * 32 + quad * 8];
        acc[u] = __builtin_amdgcn_mfma_f32_16x16x32_bf16(a2, b, acc[u], 0, 0, 0);
      }
    }
  }
#pragma unroll
  for (int u = 0; u < 2; ++u) {
#pragma unroll
    for (int reg = 0; reg < 4; ++reg) {
      int rrow = r0 + m0 + quad * 4 + reg;
      if (rrow < LL)
        part2[((size_t)blockIdx.y * LL + rrow) * HDIM + u * 16 + l16] =
            acc[u][reg];
    }
  }
}

// ------ FFN part B: combine + residual + LN2 + next qkv (bf16) + final ------
__global__ __launch_bounds__(256) void k_ffnB_qkv(float* __restrict__ x,
    const float* __restrict__ part2, const float* __restrict__ b2,
    const float* __restrict__ g, const float* __restrict__ bln,
    const float* __restrict__ qw, const float* __restrict__ qb,
    unsigned short* __restrict__ Qb, unsigned short* __restrict__ KB,
    unsigned short* __restrict__ VBt, int do_qkv,
    const float* __restrict__ cw, const float* __restrict__ cb,
    float* __restrict__ out) {
  __shared__ float xs[8][33];
  int tid = threadIdx.x;
  int r = tid >> 5, ch = tid & 31;
  int row = blockIdx.x * 8 + r;
  bool ok = row < LL;
  float s = 0.f;
  if (ok) {
#pragma unroll
    for (int q = 0; q < NSEG; ++q)
      s += part2[((size_t)q * LL + row) * HDIM + ch];
  }
  float val = ok ? (x[(size_t)row * HDIM + ch] + s + b2[ch]) : 0.f;
  float mean = val;
#pragma unroll
  for (int off = 16; off > 0; off >>= 1) mean += __shfl_xor(mean, off, 32);
  mean *= (1.f / 32.f);
  float d = val - mean;
  float var = d * d;
#pragma unroll
  for (int off = 16; off > 0; off >>= 1) var += __shfl_xor(var, off, 32);
  var *= (1.f / 32.f);
  float y = d / sqrtf(var + EPSLN) * g[ch] + bln[ch];
  if (ok) x[(size_t)row * HDIM + ch] = y;
  xs[r][ch] = ok ? y : 0.f;
  __syncthreads();
  if (!do_qkv) {
    if (blockIdx.x == 0 && r == 0) {
      float t = y * cw[ch];
#pragma unroll
      for (int off = 16; off > 0; off >>= 1) t += __shfl_xor(t, off, 32);
      if (ch == 0) {
        float z = t + cb[0];
        out[0] = 1.f / (1.f + expf(-z));
      }
    }
    return;
  }
  if (!ok) return;
#pragma unroll
  for (int t3 = 0; t3 < 3; ++t3) {
    int cc = t3 * 32 + ch;
    const float4* wr = (const float4*)(qw + (size_t)cc * HDIM);
    float acc = qb[cc];
#pragma unroll
    for (int k = 0; k < 8; ++k) {
      float4 wv = wr[k];
      acc = fmaf(xs[r][4 * k + 0], wv.x, acc);
      acc = fmaf(xs[r][4 * k + 1], wv.y, acc);
      acc = fmaf(xs[r][4 * k + 2], wv.z, acc);
      acc = fmaf(xs[r][4 * k + 3], wv.w, acc);
    }
    store_qkv_bf16(row, ch, t3, acc, Qb, KB, VBt);
  }
}

extern "C" void kernel_launch(void* const* d_in, const int* in_sizes, int n_in,
                              void* d_out, int out_size, void* d_ws, size_t ws_size,
                              hipStream_t stream) {
  const float* data  = (const float*)d_in[0];
  const float* lin_w = (const float*)d_in[1];
  const float* lin_b = (const float*)d_in[2];
  const float* qkv_w = (const float*)d_in[3];
  const float* qkv_b = (const float*)d_in[4];
  const float* out_w = (const float*)d_in[5];
  const float* out_b = (const float*)d_in[6];
  const float* ln1_g = (const float*)d_in[7];
  const float* ln1_b = (const float*)d_in[8];
  const float* ff1_w = (const float*)d_in[9];
  const float* ff1_b = (const float*)d_in[10];
  const float* ff2_w = (const float*)d_in[11];
  const float* ff2_b = (const float*)d_in[12];
  const float* ln2_g = (const float*)d_in[13];
  const float* ln2_b = (const float*)d_in[14];
  const float* cls_w = (const float*)d_in[15];
  const float* cls_b = (const float*)d_in[16];

  float* ws = (float*)d_ws;
  float* X = ws;                                       // LL*32 fp32
  unsigned short* Xb  = (unsigned short*)(X + (size_t)LL * 32);  // XROWS*32
  unsigned short* Qb  = Xb + (size_t)XROWS * 32;
  unsigned short* KB  = Qb + (size_t)QROWS * 32;       // 8*KPAD*32
  unsigned short* VBt = KB + (size_t)8 * KPAD * 32;    // 8*16*KPAD
  unsigned short* W1B = VBt + (size_t)8 * 16 * KPAD;   // NL*FFD*32
  unsigned short* W2B = W1B + (size_t)NLAYER * FFD * 32;
  float4* AP = (float4*)(((size_t)(W2B + (size_t)NLAYER * FFD * 32) + 15) &
                         ~(size_t)15);                 // NCHUNK*NHEAD*LL float4
  float* LP = (float*)(AP + (size_t)NCHUNK * NHEAD * LL);
  float* PART2 = (float*)AP;   // aliased; AP dead once oproj has run

  const int NROWB = (LL + 7) / 8;                      // 513
  const int NSETUP = 8 * KPAD * 32;                    // largest setup region

  k_setup<<<(NSETUP + 255) / 256, 256, 0, stream>>>(ff1_w, ff2_w, W1B, W2B,
                                                    Qb, KB, VBt);
  k_embed_qkv<<<NROWB, 256, 0, stream>>>(data, lin_w, lin_b, X,
                                         qkv_w, qkv_b, Qb, KB, VBt);
  for (int l = 0; l < NLAYER; ++l) {
    k_attn<<<dim3(33, NHEAD, NCHUNK), 256, 0, stream>>>(Qb, KB, VBt, LP,
                                                        (float*)AP);
    k_oproj<<<NROWB, 256, 0, stream>>>(
        LP, AP, X, Xb, out_w + (size_t)l * 32 * 32, out_b + (size_t)l * 32,
        ln1_g + (size_t)l * 32, ln1_b + (size_t)l * 32);
    k_ffnA<<<dim3((LL + RT - 1) / RT, NSEG), 256, 0, stream>>>(
        Xb, W1B + (size_t)l * FFD * 32, ff1_b + (size_t)l * FFD,
        W2B + (size_t)l * FFD * 32, PART2);
    int nl = l + 1;
    int do_qkv = (nl < NLAYER) ? 1 : 0;
    const float* qw = qkv_w + (size_t)(do_qkv ? nl : 0) * 96 * 32;
    const float* qb = qkv_b + (size_t)(do_qkv ? nl : 0) * 96;
    k_ffnB_qkv<<<NROWB, 256, 0, stream>>>(
        X, PART2, ff2_b + (size_t)l * 32,
        ln2_g + (size_t)l * 32, ln2_b + (size_t)l * 32,
        qw, qb, Qb, KB, VBt, do_qkv, cls_w, cls_b, (float*)d_out);
  }
}